// Round 6
// baseline (240.595 us; speedup 1.0000x reference)
//
#include <hip/hip_runtime.h>
#include <hip/hip_bf16.h>

#define N_ 4
#define L_ 1024
#define E_ 1024
#define H_ 32
#define HD_ 32

typedef unsigned short ushort;
typedef __attribute__((ext_vector_type(8))) short short8;   // bf16 x8 MFMA A/B frag
typedef __attribute__((ext_vector_type(4))) short short4v;  // bf16 x4
typedef __attribute__((ext_vector_type(4))) float float4v;  // MFMA C/D frag
typedef __attribute__((ext_vector_type(2))) unsigned int uint2v;

__device__ __forceinline__ ushort f2b(float f) {
    __hip_bfloat16 h = __float2bfloat16(f);
    return *reinterpret_cast<ushort*>(&h);
}

// RNE pack of two positive finite floats -> 2 bf16 in one dword
__device__ __forceinline__ unsigned packbf2(float a, float b) {
    unsigned ua = __float_as_uint(a);
    unsigned ub = __float_as_uint(b);
    ua += 0x7FFFu + ((ua >> 16) & 1u);
    ub += 0x7FFFu + ((ub >> 16) & 1u);
    return (ua >> 16) | (ub & 0xFFFF0000u);
}

__device__ __forceinline__ float fast_exp2(float x) {
#if __has_builtin(__builtin_amdgcn_exp2f)
    return __builtin_amdgcn_exp2f(x);        // raw v_exp_f32 (2^x)
#else
    return __expf(x * 0.69314718056f);       // native e^x path
#endif
}

// load 8 consecutive fp32, convert to bf16x8 frag
__device__ __forceinline__ short8 cvt8(const float* __restrict__ p) {
    float4v a = *(const float4v*)p;
    float4v b = *(const float4v*)(p + 4);
    short8 r;
    r[0] = (short)f2b(a[0]); r[1] = (short)f2b(a[1]);
    r[2] = (short)f2b(a[2]); r[3] = (short)f2b(a[3]);
    r[4] = (short)f2b(b[0]); r[5] = (short)f2b(b[1]);
    r[6] = (short)f2b(b[2]); r[7] = (short)f2b(b[3]);
    return r;
}

// ---------------------------------------------------------------------------
// Kernel 0: one-time conversions. (unchanged from R5)
// ---------------------------------------------------------------------------
__global__ __launch_bounds__(256) void convert_kernel(
    const float* __restrict__ Wv, const float* __restrict__ Wk,
    const float* __restrict__ Wq, const float* __restrict__ Wo,
    const int* __restrict__ mask,
    ushort* __restrict__ w3, ushort* __restrict__ wo_bf,
    float* __restrict__ bias_f)
{
    const int b = blockIdx.x, t = threadIdx.x;
    if (b == 0) {
        for (int i = t; i < 3 * HD_ * HD_; i += 256) {
            float v = (i < 1024) ? Wv[i] : (i < 2048 ? Wk[i - 1024] : Wq[i - 2048]);
            w3[i] = f2b(v);
        }
    } else if (b == 1) {
        for (int i = t; i < N_ * L_; i += 256)
            bias_f[i] = (mask[i] == 0) ? -1e30f : 0.0f;
    } else {
        int i = (b - 2) * 1024 + t * 4;
        float4v v = *(const float4v*)(Wo + i);
        short4v o;
        o[0] = (short)f2b(v[0]); o[1] = (short)f2b(v[1]);
        o[2] = (short)f2b(v[2]); o[3] = (short)f2b(v[3]);
        *(short4v*)(wo_bf + i) = o;
    }
}

// ---------------------------------------------------------------------------
// Kernel 1: per-head projections via MFMA, no LDS. (unchanged from R5)
// ---------------------------------------------------------------------------
__global__ __launch_bounds__(256) void proj_kernel(
    const float* __restrict__ v_in, const float* __restrict__ k_in,
    const float* __restrict__ q_in, const ushort* __restrict__ w3,
    ushort* __restrict__ vt_ws, ushort* __restrict__ k_ws,
    ushort* __restrict__ q_ws)
{
    const int n = blockIdx.z, h = blockIdx.y, l0 = blockIdx.x * 64;
    const int t = threadIdx.x, wave = t >> 6, lane = t & 63;
    const int m = lane & 15, g = lane >> 4;

    const size_t row = (size_t)(n * L_) + l0 + wave * 16 + m;
    const float* src[3] = {v_in, k_in, q_in};
    short8 A[3];
#pragma unroll
    for (int mat = 0; mat < 3; ++mat)
        A[mat] = cvt8(src[mat] + row * E_ + h * HD_ + g * 8);

    float4v acc[3][2];
#pragma unroll
    for (int mat = 0; mat < 3; ++mat)
#pragma unroll
        for (int dt = 0; dt < 2; ++dt) {
            short8 B = *(const short8*)(w3 + mat * 1024 + (dt * 16 + m) * HD_ + g * 8);
            float4v z = float4v{0.f, 0.f, 0.f, 0.f};
            acc[mat][dt] = __builtin_amdgcn_mfma_f32_16x16x32_bf16(A[mat], B, z, 0, 0, 0);
        }

    const size_t obase = (size_t)(n * H_ + h) * L_;
    const size_t vb = (size_t)(n * H_ + h) * HD_ * L_;
#pragma unroll
    for (int dt = 0; dt < 2; ++dt)
#pragma unroll
        for (int r = 0; r < 4; ++r) {
            int tok = l0 + wave * 16 + g * 4 + r;
            int d = dt * 16 + m;
            k_ws[(obase + tok) * HD_ + d] = f2b(acc[1][dt][r]);
            q_ws[(obase + tok) * HD_ + d] = f2b(acc[2][dt][r]);
            vt_ws[vb + (size_t)d * L_ + tok] = f2b(acc[0][dt][r]);
        }
}

// ---------------------------------------------------------------------------
// Kernel 2: attention, barrier-free, XCD-swizzled, S^T orientation.
// mfma(kf, qf) yields S^T: lane holds 4 CONSECUTIVE toks of one q-row ->
// float4 bias loads, paired bf16 packs, 4x ds_write_b64 (vs 16x b16),
// in-lane row-sum (no per-chunk cross-lane ops). PV reads P back as 2x
// ds_read_b128 (unchanged). Native v_exp_f32 via __builtin_amdgcn_exp2f.
// ---------------------------------------------------------------------------
__global__ __launch_bounds__(256) void attn_kernel(
    const ushort* __restrict__ q_ws, const ushort* __restrict__ k_ws,
    const ushort* __restrict__ vt_ws, const float* __restrict__ bias_f,
    ushort* __restrict__ x_ws)
{
    const int B = blockIdx.x;
    const int head = ((B >> 7) << 3) + (B & 7);   // 0..127
    const int qt = (B >> 3) & 15;
    const int n = head >> 5, h = head & 31, q0 = qt * 64;

    const int t = threadIdx.x, wave = t >> 6, lane = t & 63;
    const int m = lane & 15, g = lane >> 4;

    __shared__ ushort sP[4][16][72];   // wave-private [q][tok]; 144B rows

    const size_t base = (size_t)(n * H_ + h) * L_;
    const ushort* kb_p = k_ws + base * HD_;
    const ushort* vb_p = vt_ws + (size_t)(n * H_ + h) * HD_ * L_;
    const float* bias_p = bias_f + n * L_;

    // persistent Q B-frag: B[k=e][col=q]: lane holds Q[q=m][e=g*8..+7]
    short8 qf = *(const short8*)(q_ws + (base + q0 + wave * 16 + m) * HD_ + g * 8);

    float4v O[2];
    O[0] = float4v{0.f, 0.f, 0.f, 0.f};
    O[1] = float4v{0.f, 0.f, 0.f, 0.f};
    float rs4[4] = {0.f, 0.f, 0.f, 0.f};
    const float k1 = 0.03125f * 1.44269504f;   // (1/sqrt(E)) * log2(e)

    ushort* prow = &sP[wave][m][0];

    // preload K A-frags for chunk 0: A[row=tok][k=e]: lane = K[nb*16+m][g*8..]
    short8 kf[4];
#pragma unroll
    for (int nb = 0; nb < 4; ++nb)
        kf[nb] = *(const short8*)(kb_p + (size_t)(nb * 16 + m) * HD_ + g * 8);

    for (int c = 0; c < 16; ++c) {
        const int tok0 = c * 64;
        // ---- S^T = K * Q^T: D[row=tok local g*4+r][col=q=m] ----
        float4v S[4];
#pragma unroll
        for (int nb = 0; nb < 4; ++nb) {
            float4v z = float4v{0.f, 0.f, 0.f, 0.f};
            S[nb] = __builtin_amdgcn_mfma_f32_16x16x32_bf16(kf[nb], qf, z, 0, 0, 0);
        }
        // prefetch next chunk's K frags (wraps on last iter; branch-free)
        const int tn = ((c + 1) & 15) * 64;
#pragma unroll
        for (int nb = 0; nb < 4; ++nb)
            kf[nb] = *(const short8*)(kb_p + (size_t)(tn + nb * 16 + m) * HD_ + g * 8);
        // hoist V B-frags for this chunk (used ~150 cyc later)
        short8 vf[2][2];
#pragma unroll
        for (int kb = 0; kb < 2; ++kb)
#pragma unroll
            for (int db = 0; db < 2; ++db)
                vf[kb][db] = *(const short8*)(vb_p + (size_t)(db * 16 + m) * L_ + tok0 + kb * 32 + g * 8);

        // ---- exp + pack + b64 LDS write (4 consecutive toks per lane) ----
#pragma unroll
        for (int nb = 0; nb < 4; ++nb) {
            float4v b4 = *(const float4v*)(bias_p + tok0 + nb * 16 + g * 4);
            float p0 = fast_exp2(fmaf(S[nb][0], k1, b4[0]));
            float p1 = fast_exp2(fmaf(S[nb][1], k1, b4[1]));
            float p2 = fast_exp2(fmaf(S[nb][2], k1, b4[2]));
            float p3 = fast_exp2(fmaf(S[nb][3], k1, b4[3]));
            rs4[0] += p0; rs4[1] += p1; rs4[2] += p2; rs4[3] += p3;
            uint2v pk;
            pk[0] = packbf2(p0, p1);
            pk[1] = packbf2(p2, p3);
            *(uint2v*)(prow + nb * 16 + g * 4) = pk;   // ds_write_b64
        }

        // ---- PV: O += P(16x64) * V(64x32); same-wave LDS RAW is in-order ----
#pragma unroll
        for (int kb = 0; kb < 2; ++kb) {
            short8 af = *(const short8*)(prow + kb * 32 + g * 8);  // ds_read_b128
            O[0] = __builtin_amdgcn_mfma_f32_16x16x32_bf16(af, vf[kb][0], O[0], 0, 0, 0);
            O[1] = __builtin_amdgcn_mfma_f32_16x16x32_bf16(af, vf[kb][1], O[1], 0, 0, 0);
        }
    }

    // ---- epilogue: finish row-sums, redistribute, normalize, store ----
    float rs = (rs4[0] + rs4[1]) + (rs4[2] + rs4[3]);   // partial for q=m
    rs += __shfl_xor(rs, 16, 64);
    rs += __shfl_xor(rs, 32, 64);                       // full rowsum(q=m) in all g
    float inv[4];
#pragma unroll
    for (int r = 0; r < 4; ++r)
        inv[r] = 1.f / __shfl(rs, g * 4 + r, 64);       // rs for q=g*4+r

#pragma unroll
    for (int r = 0; r < 4; ++r) {
        size_t row = (size_t)n * L_ + q0 + wave * 16 + g * 4 + r;
#pragma unroll
        for (int db = 0; db < 2; ++db)
            x_ws[row * E_ + h * HD_ + db * 16 + m] = f2b(O[db][r] * inv[r]);
    }
}

// ---------------------------------------------------------------------------
// Kernel 3: C = X(bf16 4096x1024) @ Wo^T(bf16) + bo, fp32 out. (unchanged R5)
// ---------------------------------------------------------------------------
__global__ __launch_bounds__(256) void out_gemm_kernel(
    const ushort* __restrict__ X, const ushort* __restrict__ wo_bf,
    const float* __restrict__ bo, float* __restrict__ C)
{
    const int B = blockIdx.x;
    const int it = ((B >> 7) << 3) + (B & 7);   // 0..31
    const int jt = (B >> 3) & 15;               // 0..15
    const int i0 = it * 128, j0 = jt * 64;

    const int t = threadIdx.x, wave = t >> 6, lane = t & 63;
    const int m = lane & 15, g = lane >> 4;
    const int wr = wave >> 1, wc = wave & 1;

    __shared__ ushort sA[128][72];
    __shared__ ushort sB[64][72];

    float4v acc[4][2];
#pragma unroll
    for (int mb = 0; mb < 4; ++mb)
#pragma unroll
        for (int nb = 0; nb < 2; ++nb) acc[mb][nb] = float4v{0.f, 0.f, 0.f, 0.f};

    const int r0 = t >> 3;
    const int kc = (t & 7) * 8;

    for (int k0 = 0; k0 < E_; k0 += 64) {
        __syncthreads();
#pragma unroll
        for (int p = 0; p < 4; ++p)
            *(short8*)&sA[r0 + p * 32][kc] =
                *(const short8*)(X + (size_t)(i0 + r0 + p * 32) * E_ + k0 + kc);
#pragma unroll
        for (int p = 0; p < 2; ++p)
            *(short8*)&sB[r0 + p * 32][kc] =
                *(const short8*)(wo_bf + (size_t)(j0 + r0 + p * 32) * E_ + k0 + kc);
        __syncthreads();
#pragma unroll
        for (int kb = 0; kb < 2; ++kb) {
            short8 bfr0 = *(const short8*)&sB[wc * 32 + m][kb * 32 + g * 8];
            short8 bfr1 = *(const short8*)&sB[wc * 32 + 16 + m][kb * 32 + g * 8];
#pragma unroll
            for (int mb = 0; mb < 4; ++mb) {
                short8 afr = *(const short8*)&sA[wr * 64 + mb * 16 + m][kb * 32 + g * 8];
                acc[mb][0] = __builtin_amdgcn_mfma_f32_16x16x32_bf16(afr, bfr0, acc[mb][0], 0, 0, 0);
                acc[mb][1] = __builtin_amdgcn_mfma_f32_16x16x32_bf16(afr, bfr1, acc[mb][1], 0, 0, 0);
            }
        }
    }

#pragma unroll
    for (int nb = 0; nb < 2; ++nb) {
        int col = j0 + wc * 32 + nb * 16 + m;
        float bias = bo[col];
#pragma unroll
        for (int mb = 0; mb < 4; ++mb)
#pragma unroll
            for (int r = 0; r < 4; ++r) {
                int rowi = i0 + wr * 64 + mb * 16 + g * 4 + r;
                C[(size_t)rowi * E_ + col] = acc[mb][nb][r] + bias;
            }
    }
}

// ---------------------------------------------------------------------------
extern "C" void kernel_launch(void* const* d_in, const int* in_sizes, int n_in,
                              void* d_out, int out_size, void* d_ws, size_t ws_size,
                              hipStream_t stream) {
    const float* values = (const float*)d_in[0];
    const float* keys   = (const float*)d_in[1];
    const float* query  = (const float*)d_in[2];
    const int*   mask   = (const int*)d_in[3];
    const float* Wv     = (const float*)d_in[4];
    const float* Wk     = (const float*)d_in[5];
    const float* Wq     = (const float*)d_in[6];
    const float* Wo     = (const float*)d_in[7];
    const float* bo     = (const float*)d_in[8];
    float* out = (float*)d_out;

    const size_t M4 = (size_t)N_ * H_ * L_ * HD_;   // 4 Mi elements
    ushort* q_ws   = (ushort*)d_ws;
    ushort* k_ws   = q_ws + M4;
    ushort* vt_ws  = k_ws + M4;
    ushort* x_ws   = vt_ws + M4;
    ushort* wo_bf  = x_ws + M4;                     // 1 Mi
    ushort* w3     = wo_bf + (size_t)E_ * E_;       // 3072
    float*  bias_f = (float*)(w3 + 3 * HD_ * HD_);  // 4096 floats

    convert_kernel<<<dim3(2 + (E_ * E_) / 1024), 256, 0, stream>>>(
        Wv, Wk, Wq, Wo, mask, w3, wo_bf, bias_f);

    proj_kernel<<<dim3(L_ / 64, H_, N_), 256, 0, stream>>>(
        values, keys, query, w3, vt_ws, k_ws, q_ws);

    attn_kernel<<<dim3(2048), 256, 0, stream>>>(
        q_ws, k_ws, vt_ws, bias_f, x_ws);

    out_gemm_kernel<<<dim3(512), 256, 0, stream>>>(
        x_ws, wo_bf, bo, out);
}

// Round 7
// 192.763 us; speedup vs baseline: 1.2481x; 1.2481x over previous
//
#include <hip/hip_runtime.h>
#include <hip/hip_bf16.h>

#define N_ 4
#define L_ 1024
#define E_ 1024
#define H_ 32
#define HD_ 32

typedef unsigned short ushort;
typedef __attribute__((ext_vector_type(8))) short short8;   // bf16 x8 MFMA A/B frag
typedef __attribute__((ext_vector_type(4))) short short4v;  // bf16 x4
typedef __attribute__((ext_vector_type(4))) float float4v;  // MFMA C/D frag
typedef __attribute__((ext_vector_type(2))) unsigned int uint2v;

__device__ __forceinline__ ushort f2b(float f) {
    __hip_bfloat16 h = __float2bfloat16(f);
    return *reinterpret_cast<ushort*>(&h);
}

// RNE pack of two positive finite floats -> 2 bf16 in one dword
__device__ __forceinline__ unsigned packbf2(float a, float b) {
    unsigned ua = __float_as_uint(a);
    unsigned ub = __float_as_uint(b);
    ua += 0x7FFFu + ((ua >> 16) & 1u);
    ub += 0x7FFFu + ((ub >> 16) & 1u);
    return (ua >> 16) | (ub & 0xFFFF0000u);
}

__device__ __forceinline__ float fast_exp2(float x) {
#if __has_builtin(__builtin_amdgcn_exp2f)
    return __builtin_amdgcn_exp2f(x);        // raw v_exp_f32 (2^x)
#else
    return __expf(x * 0.69314718056f);
#endif
}

// load 8 consecutive fp32, convert to bf16x8 frag
__device__ __forceinline__ short8 cvt8(const float* __restrict__ p) {
    float4v a = *(const float4v*)p;
    float4v b = *(const float4v*)(p + 4);
    short8 r;
    r[0] = (short)f2b(a[0]); r[1] = (short)f2b(a[1]);
    r[2] = (short)f2b(a[2]); r[3] = (short)f2b(a[3]);
    r[4] = (short)f2b(b[0]); r[5] = (short)f2b(b[1]);
    r[6] = (short)f2b(b[2]); r[7] = (short)f2b(b[3]);
    return r;
}

// ---------------------------------------------------------------------------
// Kernel 0: one-time conversions. (unchanged)
// ---------------------------------------------------------------------------
__global__ __launch_bounds__(256) void convert_kernel(
    const float* __restrict__ Wv, const float* __restrict__ Wk,
    const float* __restrict__ Wq, const float* __restrict__ Wo,
    const int* __restrict__ mask,
    ushort* __restrict__ w3, ushort* __restrict__ wo_bf,
    float* __restrict__ bias_f)
{
    const int b = blockIdx.x, t = threadIdx.x;
    if (b == 0) {
        for (int i = t; i < 3 * HD_ * HD_; i += 256) {
            float v = (i < 1024) ? Wv[i] : (i < 2048 ? Wk[i - 1024] : Wq[i - 2048]);
            w3[i] = f2b(v);
        }
    } else if (b == 1) {
        for (int i = t; i < N_ * L_; i += 256)
            bias_f[i] = (mask[i] == 0) ? -1e30f : 0.0f;
    } else {
        int i = (b - 2) * 1024 + t * 4;
        float4v v = *(const float4v*)(Wo + i);
        short4v o;
        o[0] = (short)f2b(v[0]); o[1] = (short)f2b(v[1]);
        o[2] = (short)f2b(v[2]); o[3] = (short)f2b(v[3]);
        *(short4v*)(wo_bf + i) = o;
    }
}

// ---------------------------------------------------------------------------
// Kernel 1: per-head projections via MFMA, no LDS. (unchanged)
// ---------------------------------------------------------------------------
__global__ __launch_bounds__(256) void proj_kernel(
    const float* __restrict__ v_in, const float* __restrict__ k_in,
    const float* __restrict__ q_in, const ushort* __restrict__ w3,
    ushort* __restrict__ vt_ws, ushort* __restrict__ k_ws,
    ushort* __restrict__ q_ws)
{
    const int n = blockIdx.z, h = blockIdx.y, l0 = blockIdx.x * 64;
    const int t = threadIdx.x, wave = t >> 6, lane = t & 63;
    const int m = lane & 15, g = lane >> 4;

    const size_t row = (size_t)(n * L_) + l0 + wave * 16 + m;
    const float* src[3] = {v_in, k_in, q_in};
    short8 A[3];
#pragma unroll
    for (int mat = 0; mat < 3; ++mat)
        A[mat] = cvt8(src[mat] + row * E_ + h * HD_ + g * 8);

    float4v acc[3][2];
#pragma unroll
    for (int mat = 0; mat < 3; ++mat)
#pragma unroll
        for (int dt = 0; dt < 2; ++dt) {
            short8 B = *(const short8*)(w3 + mat * 1024 + (dt * 16 + m) * HD_ + g * 8);
            float4v z = float4v{0.f, 0.f, 0.f, 0.f};
            acc[mat][dt] = __builtin_amdgcn_mfma_f32_16x16x32_bf16(A[mat], B, z, 0, 0, 0);
        }

    const size_t obase = (size_t)(n * H_ + h) * L_;
    const size_t vb = (size_t)(n * H_ + h) * HD_ * L_;
#pragma unroll
    for (int dt = 0; dt < 2; ++dt)
#pragma unroll
        for (int r = 0; r < 4; ++r) {
            int tok = l0 + wave * 16 + g * 4 + r;
            int d = dt * 16 + m;
            k_ws[(obase + tok) * HD_ + d] = f2b(acc[1][dt][r]);
            q_ws[(obase + tok) * HD_ + d] = f2b(acc[2][dt][r]);
            vt_ws[vb + (size_t)d * L_ + tok] = f2b(acc[0][dt][r]);
        }
}

// ---------------------------------------------------------------------------
// Kernel 2: attention, barrier-free, XCD-swizzled, S^T orientation,
// TWO Q-tiles per wave (32 q-rows): K/V/bias loads amortized over 2 tiles,
// tile-b exp/pack VALU overlaps tile-a LDS round-trip + PV.
// grid 1024 blocks (8 q-tiles x 128 heads), block 256.
// ---------------------------------------------------------------------------
__global__ __launch_bounds__(256, 4) void attn_kernel(
    const ushort* __restrict__ q_ws, const ushort* __restrict__ k_ws,
    const ushort* __restrict__ vt_ws, const float* __restrict__ bias_f,
    ushort* __restrict__ x_ws)
{
    const int B = blockIdx.x;
    const int head = ((B >> 6) << 3) + (B & 7);   // 0..127; 8 blocks/head share XCD
    const int qt = (B >> 3) & 7;
    const int n = head >> 5, h = head & 31, q0 = qt * 128;

    const int t = threadIdx.x, wave = t >> 6, lane = t & 63;
    const int m = lane & 15, g = lane >> 4;

    __shared__ ushort sP[4][2][16][72];   // [wave][tile][q][tok], 144B rows (16B-aligned)

    const size_t base = (size_t)(n * H_ + h) * L_;
    const ushort* vb_p = vt_ws + (size_t)(n * H_ + h) * HD_ * L_;

    // persistent Q B-frags (2 tiles)
    short8 qfa = *(const short8*)(q_ws + (base + q0 + wave * 16 + m) * HD_ + g * 8);
    short8 qfb = *(const short8*)(q_ws + (base + q0 + 64 + wave * 16 + m) * HD_ + g * 8);

    float4v Oa[2], Ob[2];
    Oa[0] = float4v{0.f,0.f,0.f,0.f}; Oa[1] = float4v{0.f,0.f,0.f,0.f};
    Ob[0] = float4v{0.f,0.f,0.f,0.f}; Ob[1] = float4v{0.f,0.f,0.f,0.f};
    float rsa[4] = {0.f,0.f,0.f,0.f}, rsb[4] = {0.f,0.f,0.f,0.f};
    const float k1 = 0.03125f * 1.44269504f;   // (1/sqrt(E)) * log2(e)

    ushort* pa = &sP[wave][0][m][0];
    ushort* pb = &sP[wave][1][m][0];

    // affine-advancing pointers (no wrap: last prefetch reads 64 toks past,
    // values unused, lands in allocated workspace)
    const ushort* kp  = k_ws + base * HD_ + (size_t)m * HD_ + g * 8;   // + tok*HD
    const ushort* vp  = vb_p + (size_t)m * L_ + g * 8;                 // + db*16*L + tok
    const float*  bp  = bias_f + n * L_ + g * 4;                       // + tok

    // preload K A-frags for chunk 0
    short8 kf[4];
#pragma unroll
    for (int nb = 0; nb < 4; ++nb)
        kf[nb] = *(const short8*)(kp + (size_t)nb * 16 * HD_);
    kp += (size_t)64 * HD_;

    for (int c = 0; c < 16; ++c) {
        // ---- S^T = K * Q^T for both tiles (kf reused) ----
        float4v Sa[4], Sb[4];
#pragma unroll
        for (int nb = 0; nb < 4; ++nb) {
            float4v z = float4v{0.f,0.f,0.f,0.f};
            Sa[nb] = __builtin_amdgcn_mfma_f32_16x16x32_bf16(kf[nb], qfa, z, 0, 0, 0);
        }
#pragma unroll
        for (int nb = 0; nb < 4; ++nb) {
            float4v z = float4v{0.f,0.f,0.f,0.f};
            Sb[nb] = __builtin_amdgcn_mfma_f32_16x16x32_bf16(kf[nb], qfb, z, 0, 0, 0);
        }
        // prefetch next chunk's K frags (affine)
#pragma unroll
        for (int nb = 0; nb < 4; ++nb)
            kf[nb] = *(const short8*)(kp + (size_t)nb * 16 * HD_);
        kp += (size_t)64 * HD_;
        // V B-frags for this chunk (shared by both tiles)
        short8 vf[2][2];
#pragma unroll
        for (int kb = 0; kb < 2; ++kb)
#pragma unroll
            for (int db = 0; db < 2; ++db)
                vf[kb][db] = *(const short8*)(vp + (size_t)db * 16 * L_ + kb * 32);
        vp += 64;

        // ---- exp + pack + b64 LDS writes, both tiles (bias shared) ----
#pragma unroll
        for (int nb = 0; nb < 4; ++nb) {
            float4v b4 = *(const float4v*)(bp + nb * 16);
            float a0 = fast_exp2(fmaf(Sa[nb][0], k1, b4[0]));
            float a1 = fast_exp2(fmaf(Sa[nb][1], k1, b4[1]));
            float a2 = fast_exp2(fmaf(Sa[nb][2], k1, b4[2]));
            float a3 = fast_exp2(fmaf(Sa[nb][3], k1, b4[3]));
            rsa[0] += a0; rsa[1] += a1; rsa[2] += a2; rsa[3] += a3;
            uint2v pka; pka[0] = packbf2(a0, a1); pka[1] = packbf2(a2, a3);
            *(uint2v*)(pa + nb * 16 + g * 4) = pka;
            float e0 = fast_exp2(fmaf(Sb[nb][0], k1, b4[0]));
            float e1 = fast_exp2(fmaf(Sb[nb][1], k1, b4[1]));
            float e2 = fast_exp2(fmaf(Sb[nb][2], k1, b4[2]));
            float e3 = fast_exp2(fmaf(Sb[nb][3], k1, b4[3]));
            rsb[0] += e0; rsb[1] += e1; rsb[2] += e2; rsb[3] += e3;
            uint2v pkb; pkb[0] = packbf2(e0, e1); pkb[1] = packbf2(e2, e3);
            *(uint2v*)(pb + nb * 16 + g * 4) = pkb;
        }
        bp += 64;

        // ---- PV both tiles (same-wave in-order DS: no barrier) ----
#pragma unroll
        for (int kb = 0; kb < 2; ++kb) {
            short8 af = *(const short8*)(pa + kb * 32 + g * 8);  // ds_read_b128
            Oa[0] = __builtin_amdgcn_mfma_f32_16x16x32_bf16(af, vf[kb][0], Oa[0], 0, 0, 0);
            Oa[1] = __builtin_amdgcn_mfma_f32_16x16x32_bf16(af, vf[kb][1], Oa[1], 0, 0, 0);
        }
#pragma unroll
        for (int kb = 0; kb < 2; ++kb) {
            short8 bf = *(const short8*)(pb + kb * 32 + g * 8);
            Ob[0] = __builtin_amdgcn_mfma_f32_16x16x32_bf16(bf, vf[kb][0], Ob[0], 0, 0, 0);
            Ob[1] = __builtin_amdgcn_mfma_f32_16x16x32_bf16(bf, vf[kb][1], Ob[1], 0, 0, 0);
        }
    }

    // ---- epilogue: row-sums, redistribute, normalize, store (both tiles) ----
    float ra = (rsa[0] + rsa[1]) + (rsa[2] + rsa[3]);
    float rb = (rsb[0] + rsb[1]) + (rsb[2] + rsb[3]);
    ra += __shfl_xor(ra, 16, 64); ra += __shfl_xor(ra, 32, 64);
    rb += __shfl_xor(rb, 16, 64); rb += __shfl_xor(rb, 32, 64);
#pragma unroll
    for (int r = 0; r < 4; ++r) {
        float inva = 1.f / __shfl(ra, g * 4 + r, 64);
        float invb = 1.f / __shfl(rb, g * 4 + r, 64);
        size_t rowa = (size_t)n * L_ + q0 + wave * 16 + g * 4 + r;
        size_t rowb = rowa + 64;
#pragma unroll
        for (int db = 0; db < 2; ++db) {
            x_ws[rowa * E_ + h * HD_ + db * 16 + m] = f2b(Oa[db][r] * inva);
            x_ws[rowb * E_ + h * HD_ + db * 16 + m] = f2b(Ob[db][r] * invb);
        }
    }
}

// ---------------------------------------------------------------------------
// Kernel 3: C = X(bf16 4096x1024) @ Wo^T(bf16) + bo, fp32 out.
// 64x64 tile, BK=64, 1024 blocks (4/CU), XCD-swizzled (j-tiles of an i-tile
// share an XCD -> X fetched once, Wo L2-resident).
// ---------------------------------------------------------------------------
__global__ __launch_bounds__(256) void out_gemm_kernel(
    const ushort* __restrict__ X, const ushort* __restrict__ wo_bf,
    const float* __restrict__ bo, float* __restrict__ C)
{
    const int B = blockIdx.x;
    const int it = ((B >> 7) << 3) + (B & 7);   // 0..63
    const int jt = (B >> 3) & 15;               // 0..15
    const int i0 = it * 64, j0 = jt * 64;

    const int t = threadIdx.x, wave = t >> 6, lane = t & 63;
    const int m = lane & 15, g = lane >> 4;

    __shared__ ushort sA[64][72];
    __shared__ ushort sB[64][72];

    float4v acc[4];
#pragma unroll
    for (int nb = 0; nb < 4; ++nb) acc[nb] = float4v{0.f,0.f,0.f,0.f};

    const int r0 = t >> 2;          // 0..63
    const int c0 = (t & 3) * 16;    // 0..48

    for (int k0 = 0; k0 < E_; k0 += 64) {
        __syncthreads();
        *(short8*)&sA[r0][c0]     = *(const short8*)(X + (size_t)(i0 + r0) * E_ + k0 + c0);
        *(short8*)&sA[r0][c0 + 8] = *(const short8*)(X + (size_t)(i0 + r0) * E_ + k0 + c0 + 8);
        *(short8*)&sB[r0][c0]     = *(const short8*)(wo_bf + (size_t)(j0 + r0) * E_ + k0 + c0);
        *(short8*)&sB[r0][c0 + 8] = *(const short8*)(wo_bf + (size_t)(j0 + r0) * E_ + k0 + c0 + 8);
        __syncthreads();
#pragma unroll
        for (int kb = 0; kb < 2; ++kb) {
            short8 afr = *(const short8*)&sA[wave * 16 + m][kb * 32 + g * 8];
#pragma unroll
            for (int nb = 0; nb < 4; ++nb) {
                short8 bfr = *(const short8*)&sB[nb * 16 + m][kb * 32 + g * 8];
                acc[nb] = __builtin_amdgcn_mfma_f32_16x16x32_bf16(afr, bfr, acc[nb], 0, 0, 0);
            }
        }
    }

#pragma unroll
    for (int nb = 0; nb < 4; ++nb) {
        int col = j0 + nb * 16 + m;
        float bias = bo[col];
#pragma unroll
        for (int r = 0; r < 4; ++r) {
            int rowi = i0 + wave * 16 + g * 4 + r;
            C[(size_t)rowi * E_ + col] = acc[nb][r] + bias;
        }
    }
}

// ---------------------------------------------------------------------------
extern "C" void kernel_launch(void* const* d_in, const int* in_sizes, int n_in,
                              void* d_out, int out_size, void* d_ws, size_t ws_size,
                              hipStream_t stream) {
    const float* values = (const float*)d_in[0];
    const float* keys   = (const float*)d_in[1];
    const float* query  = (const float*)d_in[2];
    const int*   mask   = (const int*)d_in[3];
    const float* Wv     = (const float*)d_in[4];
    const float* Wk     = (const float*)d_in[5];
    const float* Wq     = (const float*)d_in[6];
    const float* Wo     = (const float*)d_in[7];
    const float* bo     = (const float*)d_in[8];
    float* out = (float*)d_out;

    const size_t M4 = (size_t)N_ * H_ * L_ * HD_;   // 4 Mi elements
    ushort* q_ws   = (ushort*)d_ws;
    ushort* k_ws   = q_ws + M4;
    ushort* vt_ws  = k_ws + M4;
    ushort* x_ws   = vt_ws + M4;
    ushort* wo_bf  = x_ws + M4;                     // 1 Mi
    ushort* w3     = wo_bf + (size_t)E_ * E_;       // 3072
    float*  bias_f = (float*)(w3 + 3 * HD_ * HD_);  // 4096 floats

    convert_kernel<<<dim3(2 + (E_ * E_) / 1024), 256, 0, stream>>>(
        Wv, Wk, Wq, Wo, mask, w3, wo_bf, bias_f);

    proj_kernel<<<dim3(L_ / 64, H_, N_), 256, 0, stream>>>(
        values, keys, query, w3, vt_ws, k_ws, q_ws);

    attn_kernel<<<dim3(1024), 256, 0, stream>>>(
        q_ws, k_ws, vt_ws, bias_f, x_ws);

    out_gemm_kernel<<<dim3(1024), 256, 0, stream>>>(
        x_ws, wo_bf, bo, out);
}